// Round 16
// baseline (114.051 us; speedup 1.0000x reference)
//
#include <hip/hip_runtime.h>
#include <hip/hip_bf16.h>

#define N_NODES 50000
#define N_EDGES 800000
#define NF 64            // IN_F == OUT_F == 64
#define BUCK_SHIFT 6
#define BUCK_SIZE 64     // rows per bucket
#define NBUK ((N_NODES + BUCK_SIZE - 1) / BUCK_SIZE)  // 782
#define CAP 1280         // LDS slots per bucket (mean 1024, sd ~32 -> +8 sigma)
#define CHUNK 4096       // edges per binning block (32 KB LDS stage)
#define BIN_BLOCKS ((N_EDGES + CHUNK - 1) / CHUNK)    // 196
#define GEMM_BLOCKS 828  // total 1024 blocks = 4/CU capacity, one round
#define TABW (NBUK + 1)  // 783 offsets per producer block
#define PER ((NBUK + 255) / 256)  // 4 hist entries per thread in block scan
#define EPT (CHUNK / 256)         // 16 edges per thread in bin half

// ---------------- kernel 1: fused producer (bin || gemm), 256 thr ----------
// (frozen from round 13 — best)
__global__ __launch_bounds__(256) void produce(
    const float* __restrict__ x, const int* __restrict__ erow,
    const int* __restrict__ ecol, const float* __restrict__ eval,
    const float* __restrict__ w, int2* __restrict__ stage1,
    int* __restrict__ tab, __hip_bfloat16* __restrict__ support) {
  __shared__ __align__(16) char smem[CHUNK * 8 + NBUK * 4 + 16];
  const int tid = threadIdx.x;
  const int lane = tid & 63;
  const int wave = tid >> 6;

  if (blockIdx.x < BIN_BLOCKS) {
    int2* sorted = (int2*)smem;            // CHUNK int2 (32 KB)
    int* hist = (int*)(smem + CHUNK * 8);  // NBUK: counts -> offsets -> cursor
    int* wsum = hist + NBUK;               // 4

    for (int t = tid; t < NBUK; t += 256) hist[t] = 0;
    __syncthreads();

    const int e0 = blockIdx.x * CHUNK;
    const int e1 = min(e0 + CHUNK, N_EDGES);

    // single pass: load edges into registers + histogram
    int rj[EPT], cj[EPT];
    float vj[EPT];
#pragma unroll
    for (int j = 0; j < EPT; ++j) {
      const int e = e0 + tid + j * 256;
      const bool ok = e < e1;
      rj[j] = ok ? erow[e] : -1;
      cj[j] = ok ? ecol[e] : 0;
      vj[j] = ok ? eval[e] : 0.f;
      if (ok) atomicAdd(&hist[rj[j] >> BUCK_SHIFT], 1);
    }
    __syncthreads();

    // block-wide exclusive scan of hist[0..NBUK)
    int loc[PER];
    int tsum = 0;
    const int i0 = tid * PER;
#pragma unroll
    for (int j = 0; j < PER; ++j) {
      const int idx = i0 + j;
      const int v = (idx < NBUK) ? hist[idx] : 0;
      loc[j] = tsum;
      tsum += v;
    }
    int sc = tsum;
#pragma unroll
    for (int off = 1; off < 64; off <<= 1) {
      const int up = __shfl_up(sc, off, 64);
      if (lane >= off) sc += up;
    }
    if (lane == 63) wsum[wave] = sc;
    __syncthreads();  // also guarantees all hist reads above are done
    int woff = 0;
#pragma unroll
    for (int k = 0; k < 4; ++k) woff += (k < wave) ? wsum[k] : 0;
    const int texcl = woff + sc - tsum;

    int* gt = tab + (size_t)blockIdx.x * TABW;
#pragma unroll
    for (int j = 0; j < PER; ++j) {
      const int idx = i0 + j;
      if (idx < NBUK) {
        const int o = texcl + loc[j];
        hist[idx] = o;  // exclusive offset; atomicAdd below makes it a cursor
        gt[idx] = o;    // coalesced table-row write
      }
    }
    if (tid == 0) gt[NBUK] = e1 - e0;
    __syncthreads();

    // place edges from registers into LDS sorted order
#pragma unroll
    for (int j = 0; j < EPT; ++j) {
      if (rj[j] >= 0) {
        const int b = rj[j] >> BUCK_SHIFT;
        const int p = atomicAdd(&hist[b], 1);
        sorted[p] = make_int2(((rj[j] & (BUCK_SIZE - 1)) << 16) | cj[j],
                              __float_as_int(vj[j]));
      }
    }
    __syncthreads();

    // fully-coalesced write-out of the sorted run
    const int n = e1 - e0;
    int2* gs = stage1 + (size_t)blockIdx.x * CHUNK;
    for (int i = tid; i < n; i += 256) gs[i] = sorted[i];
  } else {
    // ---- gemm half: 2-row interleave ----
    float wcol[NF];
#pragma unroll
    for (int k = 0; k < NF; ++k) wcol[k] = w[k * NF + lane];

    const int wid = (blockIdx.x - BIN_BLOCKS) * 4 + wave;
    const int nw = GEMM_BLOCKS * 4;  // 3312 waves
    for (int row = wid; row < N_NODES; row += 2 * nw) {
      const int rA = __builtin_amdgcn_readfirstlane(row);
      const int rB_raw = row + nw;
      const bool hasB = rB_raw < N_NODES;
      const int rB = __builtin_amdgcn_readfirstlane(hasB ? rB_raw : rA);
      const float* xA = x + (size_t)rA * NF;
      const float* xB = x + (size_t)rB * NF;
      float a0 = 0.f, a1 = 0.f, a2 = 0.f, a3 = 0.f;
      float b0 = 0.f, b1 = 0.f, b2 = 0.f, b3 = 0.f;
#pragma unroll
      for (int k = 0; k < NF; k += 4) {
        a0 = fmaf(xA[k + 0], wcol[k + 0], a0);
        b0 = fmaf(xB[k + 0], wcol[k + 0], b0);
        a1 = fmaf(xA[k + 1], wcol[k + 1], a1);
        b1 = fmaf(xB[k + 1], wcol[k + 1], b1);
        a2 = fmaf(xA[k + 2], wcol[k + 2], a2);
        b2 = fmaf(xB[k + 2], wcol[k + 2], b2);
        a3 = fmaf(xA[k + 3], wcol[k + 3], a3);
        b3 = fmaf(xB[k + 3], wcol[k + 3], b3);
      }
      support[(size_t)rA * NF + lane] = __float2bfloat16((a0 + a1) + (a2 + a3));
      if (hasB)
        support[(size_t)rB * NF + lane] =
            __float2bfloat16((b0 + b1) + (b2 + b3));
    }
  }
}

// ---------------- kernel 2: segmented gather + sort-in-LDS + register SpMM --
// One 512-thread block per 64-row bucket. NEW vs r15: accumulate processes
// TWO rows concurrently (dual accumulator sets; fused uniform-bound loop
// issues row-A's 4 gathers and row-B's 4 gathers back-to-back -> 8 loads in
// flight, 4 serial steps/wave instead of 8).
__global__ __launch_bounds__(512) void spmm_sorted(
    const __hip_bfloat16* __restrict__ support, const int* __restrict__ tab,
    const int2* __restrict__ stage1, const float* __restrict__ bias,
    float* __restrict__ out) {
  __shared__ int2 srt[CAP];              // 10 KB
  __shared__ int segpos[BIN_BLOCKS + 1]; // exclusive slot positions (197)
  __shared__ int segst[BIN_BLOCKS];      // segment start within producer row
  __shared__ int rcnt[BUCK_SIZE];
  __shared__ int rofs[BUCK_SIZE];
  __shared__ int rcur[BUCK_SIZE];
  __shared__ int wsum[8];
  const int b = blockIdx.x;
  const int tid = threadIdx.x;
  const int lane = tid & 63;
  const int wave = tid >> 6;

  if (tid < BUCK_SIZE) rcnt[tid] = 0;

  // segment descriptor for producer-block tid (adjacent table entries)
  int st = 0, c = 0;
  if (tid < BIN_BLOCKS) {
    const int* gt = tab + (size_t)tid * TABW;
    st = gt[b];
    c = gt[b + 1] - st;
  }
  // block scan of counts -> exclusive slot position
  int sc = c;
#pragma unroll
  for (int off = 1; off < 64; off <<= 1) {
    const int up = __shfl_up(sc, off, 64);
    if (lane >= off) sc += up;
  }
  if (lane == 63) wsum[wave] = sc;
  __syncthreads();
  int woff = 0;
#pragma unroll
  for (int k = 0; k < 8; ++k) woff += (k < wave) ? wsum[k] : 0;
  if (tid < BIN_BLOCKS) {
    segpos[tid] = woff + sc - c;
    segst[tid] = st;
  }
  if (tid == 511) segpos[BIN_BLOCKS] = woff + sc;  // total count
  __syncthreads();

  const int cnt = min(segpos[BIN_BLOCKS], CAP);

  // parallel gather to REGISTERS: slot i -> binary search owning segment
  // (8 LDS probes), one coalesced global load, LDS row-count.
  int2 mreg[3];
#pragma unroll
  for (int q = 0; q < 3; ++q) {
    const int i = tid + q * 512;
    mreg[q] = make_int2(-1, 0);
    if (i < cnt) {
      int lo = 0, hi = BIN_BLOCKS - 1;
      while (lo < hi) {
        const int mid = (lo + hi + 1) >> 1;
        if (segpos[mid] <= i) lo = mid;
        else hi = mid - 1;
      }
      const int k = i - segpos[lo];
      const int2 m = stage1[(size_t)lo * CHUNK + segst[lo] + k];
      mreg[q] = m;
      atomicAdd(&rcnt[m.x >> 16], 1);
    }
  }
  __syncthreads();

  // exclusive scan of 64 row counters (wave 0)
  if (tid < 64) {
    const int v = rcnt[lane];
    int s2 = v;
#pragma unroll
    for (int off = 1; off < 64; off <<= 1) {
      const int up = __shfl_up(s2, off, 64);
      if (lane >= off) s2 += up;
    }
    rofs[lane] = s2 - v;
    rcur[lane] = s2 - v;
  }
  __syncthreads();

  // place row-sorted directly from registers
#pragma unroll
  for (int q = 0; q < 3; ++q) {
    if (mreg[q].x >= 0) {
      const int p = atomicAdd(&rcur[mreg[q].x >> 16], 1);
      srt[p] = mreg[q];
    }
  }
  __syncthreads();

  // per-row accumulation: 2 rows concurrently, 4 edges per wave-gather each.
  const int grp = lane >> 4;  // 0..3: edge slot within a gather batch
  const int sub = lane & 15;  // feature quad: features 4*sub .. 4*sub+3
  const int row0 = b << BUCK_SHIFT;
  const float4 bv4 = reinterpret_cast<const float4*>(bias)[sub];
#pragma unroll
  for (int rr = 0; rr < 8; rr += 2) {
    const int rlA = wave * 8 + rr;
    const int rlB = rlA + 1;
    const int rowA = row0 + rlA;
    if (rowA >= N_NODES) break;  // wave-uniform
    const int rowB = row0 + rlB;
    const bool hasB = rowB < N_NODES;  // wave-uniform
    const int sA = __builtin_amdgcn_readfirstlane(rofs[rlA]);
    const int eA = __builtin_amdgcn_readfirstlane(rofs[rlA] + rcnt[rlA]);
    const int sB = hasB ? __builtin_amdgcn_readfirstlane(rofs[rlB]) : 0;
    const int eB =
        hasB ? __builtin_amdgcn_readfirstlane(rofs[rlB] + rcnt[rlB]) : 0;
    float a0 = 0.f, a1 = 0.f, a2 = 0.f, a3 = 0.f;
    float b0 = 0.f, b1 = 0.f, b2 = 0.f, b3 = 0.f;
    int iA = sA, iB = sB;
    // fused main loop: both rows' gather batches issued before either's FMAs
    while (true) {
      const bool doA = iA + 16 <= eA;
      const bool doB = iB + 16 <= eB;
      if (!doA && !doB) break;
      if (doA) {
#pragma unroll
        for (int q = 0; q < 4; ++q) {
          const int2 m = srt[iA + 4 * q + grp];
          const float v = __int_as_float(m.y);
          const uint2 t = *reinterpret_cast<const uint2*>(
              support + (size_t)(m.x & 0xFFFF) * NF + sub * 4);
          a0 = fmaf(v, __int_as_float(t.x << 16), a0);
          a1 = fmaf(v, __int_as_float((int)(t.x & 0xFFFF0000u)), a1);
          a2 = fmaf(v, __int_as_float(t.y << 16), a2);
          a3 = fmaf(v, __int_as_float((int)(t.y & 0xFFFF0000u)), a3);
        }
        iA += 16;
      }
      if (doB) {
#pragma unroll
        for (int q = 0; q < 4; ++q) {
          const int2 m = srt[iB + 4 * q + grp];
          const float v = __int_as_float(m.y);
          const uint2 t = *reinterpret_cast<const uint2*>(
              support + (size_t)(m.x & 0xFFFF) * NF + sub * 4);
          b0 = fmaf(v, __int_as_float(t.x << 16), b0);
          b1 = fmaf(v, __int_as_float((int)(t.x & 0xFFFF0000u)), b1);
          b2 = fmaf(v, __int_as_float(t.y << 16), b2);
          b3 = fmaf(v, __int_as_float((int)(t.y & 0xFFFF0000u)), b3);
        }
        iB += 16;
      }
    }
    // tails (4 edges at a time, predicated per group)
    for (; iA < eA; iA += 4) {
      const int idx = iA + grp;
      if (idx < eA) {
        const int2 m = srt[idx];
        const float v = __int_as_float(m.y);
        const uint2 t = *reinterpret_cast<const uint2*>(
            support + (size_t)(m.x & 0xFFFF) * NF + sub * 4);
        a0 = fmaf(v, __int_as_float(t.x << 16), a0);
        a1 = fmaf(v, __int_as_float((int)(t.x & 0xFFFF0000u)), a1);
        a2 = fmaf(v, __int_as_float(t.y << 16), a2);
        a3 = fmaf(v, __int_as_float((int)(t.y & 0xFFFF0000u)), a3);
      }
    }
    for (; iB < eB; iB += 4) {
      const int idx = iB + grp;
      if (idx < eB) {
        const int2 m = srt[idx];
        const float v = __int_as_float(m.y);
        const uint2 t = *reinterpret_cast<const uint2*>(
            support + (size_t)(m.x & 0xFFFF) * NF + sub * 4);
        b0 = fmaf(v, __int_as_float(t.x << 16), b0);
        b1 = fmaf(v, __int_as_float((int)(t.x & 0xFFFF0000u)), b1);
        b2 = fmaf(v, __int_as_float(t.y << 16), b2);
        b3 = fmaf(v, __int_as_float((int)(t.y & 0xFFFF0000u)), b3);
      }
    }
    // combine group-partials for both rows (sub preserved under xor 16/32)
    a0 += __shfl_xor(a0, 16, 64);
    a1 += __shfl_xor(a1, 16, 64);
    a2 += __shfl_xor(a2, 16, 64);
    a3 += __shfl_xor(a3, 16, 64);
    a0 += __shfl_xor(a0, 32, 64);
    a1 += __shfl_xor(a1, 32, 64);
    a2 += __shfl_xor(a2, 32, 64);
    a3 += __shfl_xor(a3, 32, 64);
    b0 += __shfl_xor(b0, 16, 64);
    b1 += __shfl_xor(b1, 16, 64);
    b2 += __shfl_xor(b2, 16, 64);
    b3 += __shfl_xor(b3, 16, 64);
    b0 += __shfl_xor(b0, 32, 64);
    b1 += __shfl_xor(b1, 32, 64);
    b2 += __shfl_xor(b2, 32, 64);
    b3 += __shfl_xor(b3, 32, 64);
    if (grp == 0) {
      float4 oA;
      oA.x = a0 + bv4.x;
      oA.y = a1 + bv4.y;
      oA.z = a2 + bv4.z;
      oA.w = a3 + bv4.w;
      reinterpret_cast<float4*>(out + (size_t)rowA * NF)[sub] = oA;
      if (hasB) {
        float4 oB;
        oB.x = b0 + bv4.x;
        oB.y = b1 + bv4.y;
        oB.z = b2 + bv4.z;
        oB.w = b3 + bv4.w;
        reinterpret_cast<float4*>(out + (size_t)rowB * NF)[sub] = oB;
      }
    }
  }
}

// -------------------- launch --------------------
extern "C" void kernel_launch(void* const* d_in, const int* in_sizes, int n_in,
                              void* d_out, int out_size, void* d_ws,
                              size_t ws_size, hipStream_t stream) {
  const float* x = (const float*)d_in[0];
  const int* erow = (const int*)d_in[1];
  const int* ecol = (const int*)d_in[2];
  const float* eval = (const float*)d_in[3];
  const float* w = (const float*)d_in[4];
  const float* bias = (const float*)d_in[5];
  float* out = (float*)d_out;

  // workspace layout (16B-aligned)
  char* ws = (char*)d_ws;
  __hip_bfloat16* support = (__hip_bfloat16*)(ws);  //  6,400,000 B
  int2* stage1 = (int2*)(ws + 6400000);             //  6,422,528 B (196*4096*8)
  int* tab = (int*)(ws + 12822528);                 //    613,872 B (196*783*4)
  // total ~13.44 MB; no memset needed (tab fully written by produce)

  produce<<<BIN_BLOCKS + GEMM_BLOCKS, 256, 0, stream>>>(
      x, erow, ecol, eval, w, stage1, tab, support);
  spmm_sorted<<<NBUK, 512, 0, stream>>>(support, tab, stage1, bias, out);
}

// Round 17
// 110.358 us; speedup vs baseline: 1.0335x; 1.0335x over previous
//
#include <hip/hip_runtime.h>
#include <hip/hip_bf16.h>

#define N_NODES 50000
#define N_EDGES 800000
#define NF 64            // IN_F == OUT_F == 64
#define BUCK_SHIFT 6
#define BUCK_SIZE 64     // rows per bucket
#define NBUK ((N_NODES + BUCK_SIZE - 1) / BUCK_SIZE)  // 782
#define CAP 1280         // LDS slots per bucket (mean 1024, sd ~32 -> +8 sigma)
#define CHUNK 4096       // edges per binning block (32 KB LDS stage)
#define BIN_BLOCKS ((N_EDGES + CHUNK - 1) / CHUNK)    // 196
#define GEMM_BLOCKS 828  // total 1024 blocks = 4/CU capacity, one round
#define TABW (NBUK + 1)  // 783 offsets per producer block
#define PER ((NBUK + 255) / 256)  // 4 hist entries per thread in block scan
#define EPT (CHUNK / 256)         // 16 edges per thread in bin half

// ---------------- kernel 1: fused producer (bin || gemm), 256 thr ----------
// (frozen from round 13 — best)
__global__ __launch_bounds__(256) void produce(
    const float* __restrict__ x, const int* __restrict__ erow,
    const int* __restrict__ ecol, const float* __restrict__ eval,
    const float* __restrict__ w, int2* __restrict__ stage1,
    int* __restrict__ tab, __hip_bfloat16* __restrict__ support) {
  __shared__ __align__(16) char smem[CHUNK * 8 + NBUK * 4 + 16];
  const int tid = threadIdx.x;
  const int lane = tid & 63;
  const int wave = tid >> 6;

  if (blockIdx.x < BIN_BLOCKS) {
    int2* sorted = (int2*)smem;            // CHUNK int2 (32 KB)
    int* hist = (int*)(smem + CHUNK * 8);  // NBUK: counts -> offsets -> cursor
    int* wsum = hist + NBUK;               // 4

    for (int t = tid; t < NBUK; t += 256) hist[t] = 0;
    __syncthreads();

    const int e0 = blockIdx.x * CHUNK;
    const int e1 = min(e0 + CHUNK, N_EDGES);

    // single pass: load edges into registers + histogram
    int rj[EPT], cj[EPT];
    float vj[EPT];
#pragma unroll
    for (int j = 0; j < EPT; ++j) {
      const int e = e0 + tid + j * 256;
      const bool ok = e < e1;
      rj[j] = ok ? erow[e] : -1;
      cj[j] = ok ? ecol[e] : 0;
      vj[j] = ok ? eval[e] : 0.f;
      if (ok) atomicAdd(&hist[rj[j] >> BUCK_SHIFT], 1);
    }
    __syncthreads();

    // block-wide exclusive scan of hist[0..NBUK)
    int loc[PER];
    int tsum = 0;
    const int i0 = tid * PER;
#pragma unroll
    for (int j = 0; j < PER; ++j) {
      const int idx = i0 + j;
      const int v = (idx < NBUK) ? hist[idx] : 0;
      loc[j] = tsum;
      tsum += v;
    }
    int sc = tsum;
#pragma unroll
    for (int off = 1; off < 64; off <<= 1) {
      const int up = __shfl_up(sc, off, 64);
      if (lane >= off) sc += up;
    }
    if (lane == 63) wsum[wave] = sc;
    __syncthreads();  // also guarantees all hist reads above are done
    int woff = 0;
#pragma unroll
    for (int k = 0; k < 4; ++k) woff += (k < wave) ? wsum[k] : 0;
    const int texcl = woff + sc - tsum;

    int* gt = tab + (size_t)blockIdx.x * TABW;
#pragma unroll
    for (int j = 0; j < PER; ++j) {
      const int idx = i0 + j;
      if (idx < NBUK) {
        const int o = texcl + loc[j];
        hist[idx] = o;  // exclusive offset; atomicAdd below makes it a cursor
        gt[idx] = o;    // coalesced table-row write
      }
    }
    if (tid == 0) gt[NBUK] = e1 - e0;
    __syncthreads();

    // place edges from registers into LDS sorted order
#pragma unroll
    for (int j = 0; j < EPT; ++j) {
      if (rj[j] >= 0) {
        const int b = rj[j] >> BUCK_SHIFT;
        const int p = atomicAdd(&hist[b], 1);
        sorted[p] = make_int2(((rj[j] & (BUCK_SIZE - 1)) << 16) | cj[j],
                              __float_as_int(vj[j]));
      }
    }
    __syncthreads();

    // fully-coalesced write-out of the sorted run
    const int n = e1 - e0;
    int2* gs = stage1 + (size_t)blockIdx.x * CHUNK;
    for (int i = tid; i < n; i += 256) gs[i] = sorted[i];
  } else {
    // ---- gemm half: 2-row interleave ----
    float wcol[NF];
#pragma unroll
    for (int k = 0; k < NF; ++k) wcol[k] = w[k * NF + lane];

    const int wid = (blockIdx.x - BIN_BLOCKS) * 4 + wave;
    const int nw = GEMM_BLOCKS * 4;  // 3312 waves
    for (int row = wid; row < N_NODES; row += 2 * nw) {
      const int rA = __builtin_amdgcn_readfirstlane(row);
      const int rB_raw = row + nw;
      const bool hasB = rB_raw < N_NODES;
      const int rB = __builtin_amdgcn_readfirstlane(hasB ? rB_raw : rA);
      const float* xA = x + (size_t)rA * NF;
      const float* xB = x + (size_t)rB * NF;
      float a0 = 0.f, a1 = 0.f, a2 = 0.f, a3 = 0.f;
      float b0 = 0.f, b1 = 0.f, b2 = 0.f, b3 = 0.f;
#pragma unroll
      for (int k = 0; k < NF; k += 4) {
        a0 = fmaf(xA[k + 0], wcol[k + 0], a0);
        b0 = fmaf(xB[k + 0], wcol[k + 0], b0);
        a1 = fmaf(xA[k + 1], wcol[k + 1], a1);
        b1 = fmaf(xB[k + 1], wcol[k + 1], b1);
        a2 = fmaf(xA[k + 2], wcol[k + 2], a2);
        b2 = fmaf(xB[k + 2], wcol[k + 2], b2);
        a3 = fmaf(xA[k + 3], wcol[k + 3], a3);
        b3 = fmaf(xB[k + 3], wcol[k + 3], b3);
      }
      support[(size_t)rA * NF + lane] = __float2bfloat16((a0 + a1) + (a2 + a3));
      if (hasB)
        support[(size_t)rB * NF + lane] =
            __float2bfloat16((b0 + b1) + (b2 + b3));
    }
  }
}

// ---------------- kernel 2: segmented gather + sort-in-LDS + register SpMM --
// (frozen from round 15 — best: 4 edges per wave-gather, lane groups of 16,
// uint2 bf16x4 payload per lane, shfl_xor combine, float4 store.)
__global__ __launch_bounds__(512) void spmm_sorted(
    const __hip_bfloat16* __restrict__ support, const int* __restrict__ tab,
    const int2* __restrict__ stage1, const float* __restrict__ bias,
    float* __restrict__ out) {
  __shared__ int2 srt[CAP];              // 10 KB
  __shared__ int segpos[BIN_BLOCKS + 1]; // exclusive slot positions (197)
  __shared__ int segst[BIN_BLOCKS];      // segment start within producer row
  __shared__ int rcnt[BUCK_SIZE];
  __shared__ int rofs[BUCK_SIZE];
  __shared__ int rcur[BUCK_SIZE];
  __shared__ int wsum[8];
  const int b = blockIdx.x;
  const int tid = threadIdx.x;
  const int lane = tid & 63;
  const int wave = tid >> 6;

  if (tid < BUCK_SIZE) rcnt[tid] = 0;

  // segment descriptor for producer-block tid (adjacent table entries)
  int st = 0, c = 0;
  if (tid < BIN_BLOCKS) {
    const int* gt = tab + (size_t)tid * TABW;
    st = gt[b];
    c = gt[b + 1] - st;
  }
  // block scan of counts -> exclusive slot position
  int sc = c;
#pragma unroll
  for (int off = 1; off < 64; off <<= 1) {
    const int up = __shfl_up(sc, off, 64);
    if (lane >= off) sc += up;
  }
  if (lane == 63) wsum[wave] = sc;
  __syncthreads();
  int woff = 0;
#pragma unroll
  for (int k = 0; k < 8; ++k) woff += (k < wave) ? wsum[k] : 0;
  if (tid < BIN_BLOCKS) {
    segpos[tid] = woff + sc - c;
    segst[tid] = st;
  }
  if (tid == 511) segpos[BIN_BLOCKS] = woff + sc;  // total count
  __syncthreads();

  const int cnt = min(segpos[BIN_BLOCKS], CAP);

  // parallel gather to REGISTERS: slot i -> binary search owning segment
  // (8 LDS probes), one coalesced global load, LDS row-count.
  int2 mreg[3];
#pragma unroll
  for (int q = 0; q < 3; ++q) {
    const int i = tid + q * 512;
    mreg[q] = make_int2(-1, 0);
    if (i < cnt) {
      int lo = 0, hi = BIN_BLOCKS - 1;
      while (lo < hi) {
        const int mid = (lo + hi + 1) >> 1;
        if (segpos[mid] <= i) lo = mid;
        else hi = mid - 1;
      }
      const int k = i - segpos[lo];
      const int2 m = stage1[(size_t)lo * CHUNK + segst[lo] + k];
      mreg[q] = m;
      atomicAdd(&rcnt[m.x >> 16], 1);
    }
  }
  __syncthreads();

  // exclusive scan of 64 row counters (wave 0)
  if (tid < 64) {
    const int v = rcnt[lane];
    int s2 = v;
#pragma unroll
    for (int off = 1; off < 64; off <<= 1) {
      const int up = __shfl_up(s2, off, 64);
      if (lane >= off) s2 += up;
    }
    rofs[lane] = s2 - v;
    rcur[lane] = s2 - v;
  }
  __syncthreads();

  // place row-sorted directly from registers
#pragma unroll
  for (int q = 0; q < 3; ++q) {
    if (mreg[q].x >= 0) {
      const int p = atomicAdd(&rcur[mreg[q].x >> 16], 1);
      srt[p] = mreg[q];
    }
  }
  __syncthreads();

  // per-row accumulation: 8 rows/wave; 4 edges per wave-gather.
  const int grp = lane >> 4;  // 0..3: edge slot within a gather batch
  const int sub = lane & 15;  // feature quad: features 4*sub .. 4*sub+3
  const int row0 = b << BUCK_SHIFT;
  const float4 bv4 = reinterpret_cast<const float4*>(bias)[sub];
#pragma unroll
  for (int rr = 0; rr < 8; ++rr) {
    const int rl = wave * 8 + rr;
    const int row = row0 + rl;
    if (row >= N_NODES) break;  // wave-uniform
    const int s = __builtin_amdgcn_readfirstlane(rofs[rl]);
    const int e = __builtin_amdgcn_readfirstlane(rofs[rl] + rcnt[rl]);
    float a0 = 0.f, a1 = 0.f, a2 = 0.f, a3 = 0.f;
    int i = s;
    // main: 16 edges per iteration, 4 per group, all 4 gathers in flight
    for (; i + 16 <= e; i += 16) {
#pragma unroll
      for (int q = 0; q < 4; ++q) {
        const int2 m = srt[i + 4 * q + grp];  // 16-lane broadcast read
        const float v = __int_as_float(m.y);
        const uint2 t = *reinterpret_cast<const uint2*>(
            support + (size_t)(m.x & 0xFFFF) * NF + sub * 4);
        a0 = fmaf(v, __int_as_float(t.x << 16), a0);
        a1 = fmaf(v, __int_as_float((int)(t.x & 0xFFFF0000u)), a1);
        a2 = fmaf(v, __int_as_float(t.y << 16), a2);
        a3 = fmaf(v, __int_as_float((int)(t.y & 0xFFFF0000u)), a3);
      }
    }
    // tail: 4 edges at a time (one per group), predicated
    for (; i < e; i += 4) {
      const int idx = i + grp;
      if (idx < e) {
        const int2 m = srt[idx];
        const float v = __int_as_float(m.y);
        const uint2 t = *reinterpret_cast<const uint2*>(
            support + (size_t)(m.x & 0xFFFF) * NF + sub * 4);
        a0 = fmaf(v, __int_as_float(t.x << 16), a0);
        a1 = fmaf(v, __int_as_float((int)(t.x & 0xFFFF0000u)), a1);
        a2 = fmaf(v, __int_as_float(t.y << 16), a2);
        a3 = fmaf(v, __int_as_float((int)(t.y & 0xFFFF0000u)), a3);
      }
    }
    // combine the 4 group-partials (sub preserved under xor 16/32)
    a0 += __shfl_xor(a0, 16, 64);
    a1 += __shfl_xor(a1, 16, 64);
    a2 += __shfl_xor(a2, 16, 64);
    a3 += __shfl_xor(a3, 16, 64);
    a0 += __shfl_xor(a0, 32, 64);
    a1 += __shfl_xor(a1, 32, 64);
    a2 += __shfl_xor(a2, 32, 64);
    a3 += __shfl_xor(a3, 32, 64);
    if (grp == 0) {
      float4 o;
      o.x = a0 + bv4.x;
      o.y = a1 + bv4.y;
      o.z = a2 + bv4.z;
      o.w = a3 + bv4.w;
      reinterpret_cast<float4*>(out + (size_t)row * NF)[sub] = o;
    }
  }
}

// -------------------- launch --------------------
extern "C" void kernel_launch(void* const* d_in, const int* in_sizes, int n_in,
                              void* d_out, int out_size, void* d_ws,
                              size_t ws_size, hipStream_t stream) {
  const float* x = (const float*)d_in[0];
  const int* erow = (const int*)d_in[1];
  const int* ecol = (const int*)d_in[2];
  const float* eval = (const float*)d_in[3];
  const float* w = (const float*)d_in[4];
  const float* bias = (const float*)d_in[5];
  float* out = (float*)d_out;

  // workspace layout (16B-aligned)
  char* ws = (char*)d_ws;
  __hip_bfloat16* support = (__hip_bfloat16*)(ws);  //  6,400,000 B
  int2* stage1 = (int2*)(ws + 6400000);             //  6,422,528 B (196*4096*8)
  int* tab = (int*)(ws + 12822528);                 //    613,872 B (196*783*4)
  // total ~13.44 MB; no memset needed (tab fully written by produce)

  produce<<<BIN_BLOCKS + GEMM_BLOCKS, 256, 0, stream>>>(
      x, erow, ecol, eval, w, stage1, tab, support);
  spmm_sorted<<<NBUK, 512, 0, stream>>>(support, tab, stage1, bias, out);
}